// Round 13
// baseline (272.873 us; speedup 1.0000x reference)
//
#include <hip/hip_runtime.h>

// Problem constants
#define BATCH 2
#define LSEQ 384
#define NHID 512
#define NH 8
#define DH 64
#define BH (BATCH*NH)          // 16
#define XELEMS ((size_t)768 * NHID)        // 393216 (x output elems)
#define TQ 8                   // q-rows per attn block
#define QTILES (LSEQ/TQ)       // 48

typedef unsigned short ushort_t;
typedef __attribute__((ext_vector_type(8))) short bf16x8;
typedef __attribute__((ext_vector_type(4))) float f32x4;

__device__ __forceinline__ float bf2f(ushort_t u) {
    unsigned int v = ((unsigned int)u) << 16;
    return __uint_as_float(v);
}
__device__ __forceinline__ ushort_t f2bf(float f) {
    unsigned int u = __float_as_uint(f);
    unsigned int lsb = (u >> 16) & 1u;
    u += 0x7fffu + lsb;           // round-to-nearest-even
    return (ushort_t)(u >> 16);
}
// RNE bf16 pair-pack: 2x add + v_perm (ushort0=bf16(a), ushort1=bf16(b))
__device__ __forceinline__ unsigned pk_bf16(float a, float b) {
    unsigned ua = __float_as_uint(a), ub = __float_as_uint(b);
    ua += 0x7fffu + ((ua >> 16) & 1u);
    ub += 0x7fffu + ((ub >> 16) & 1u);
    return __builtin_amdgcn_perm(ub, ua, 0x07060302);
}
__device__ __forceinline__ float ld1(const void* p, size_t i, int f) {
    return f ? ((const float*)p)[i] : bf2f(((const ushort_t*)p)[i]);
}
__device__ __forceinline__ float4 ld4(const void* p, size_t i, int f) {
    if (f) return ((const float4*)p)[i >> 2];
    ushort4 u = ((const ushort4*)p)[i >> 2];
    return make_float4(bf2f(u.x), bf2f(u.y), bf2f(u.z), bf2f(u.w));
}
__device__ __forceinline__ int block_detect(const unsigned int* q, int* cnt) {
    int t = threadIdx.x;
    if (t == 0) *cnt = 0;
    __syncthreads();
    int n = blockDim.x < 256 ? blockDim.x : 256;
    if (t < n) {
        unsigned int elo = (q[t] >> 7) & 0xFFu;
        if (elo >= 100u && elo <= 150u) atomicAdd(cnt, 1);
    }
    __syncthreads();
    return (*cnt * 2 > n) ? 0 : 1;     // 0 = bf16-packed, 1 = fp32
}
__device__ __forceinline__ uint4 packu4(float4 a, float4 b) {
    uint4 r;
    r.x = pk_bf16(a.x, a.y); r.y = pk_bf16(a.z, a.w);
    r.z = pk_bf16(b.x, b.y); r.w = pk_bf16(b.z, b.w);
    return r;
}
__device__ __forceinline__ bf16x8 pack_bf8(float4 a, float4 b) {
    union { uint4 u; bf16x8 v; } r;
    r.u = packu4(a, b);
    return r.v;
}

// ---------------- workspace layout (float offsets) ----------------
#define OFF_ETQ   16                  // Etq = exp(2 tq)  [bh][l][d]
#define OFF_ETK   (16 + 393216)       // Etk = exp(2 tk)  [bh][l][d] (row-major)
#define OFF_VH    (16 + 2*393216)     // V                [bh][l][d]
#define OFF_XH    (16 + 3*393216)     // context [B,L,H,D]

#define LDSTR 72   // LDS row stride in ushorts (144 B)

// ---------------------------------------------------------------------------
// Kernel 1: QKV projection via bf16 MFMA (r12, unchanged). 32x64 tile,
// 128 thr, K=512 step 64, reg prefetch. Modes 0/1 fold W1/W2 in-register and
// write Etq/Etk row-major; mode 2 writes V + bv.
// ---------------------------------------------------------------------------
__global__ __launch_bounds__(128) void gemm_qkv(
    const void* qp, const void* kp, const void* vp,
    const void* Wqp, const void* Wkp, const void* Wvp,
    const void* W1p, const void* W2p,
    const void* bqp, const void* bkp, const void* b1p, const void* b2p,
    const void* bvp, float* __restrict__ ws)
{
    __shared__ int s_cnt;
    __shared__ ushort_t smA[32 * LDSTR];
    __shared__ ushort_t smB[64 * LDSTR];
    __shared__ float biasF[64];
    const int f = block_detect((const unsigned int*)qp, &s_cnt);

    const int mode = blockIdx.z;
    const void* A = (mode == 0) ? qp : (mode == 1) ? kp : vp;
    const void* W = (mode == 0) ? Wqp : (mode == 1) ? Wkp : Wvp;
    const void* W1x = (mode == 1) ? W2p : W1p;

    const int h    = blockIdx.x;
    const int col0 = h * 64;
    const int row0 = blockIdx.y * 32;
    const int t = threadIdx.x;
    const int w = t >> 6, l16 = t & 15, quad = (t & 63) >> 4;

    if (t < 64) {
        if (mode == 2) {
            biasF[t] = ld1(bvp, col0 + t, f);
        } else {
            const void* b1x = (mode == 1) ? b2p : b1p;
            const void* bx  = (mode == 1) ? bkp : bqp;
            float s = ld1(b1x, t, f);
            for (int j = 0; j < 64; j++)
                s = fmaf(ld1(W1x, (size_t)t * 64 + j, f), ld1(bx, h * 64 + j, f), s);
            biasF[t] = s;
        }
    }

    const int arow = t >> 2, acol = (t & 3) * 16;
    const int brow = t >> 1, bcol = (t & 1) * 32;
    const size_t abase = (size_t)(row0 + arow) * 512 + acol;
    const size_t bbase = (size_t)(col0 + brow) * 512 + bcol;

    float4 a4[4], b4[8];
    #pragma unroll
    for (int i = 0; i < 4; i++) a4[i] = ld4(A, abase + i * 4, f);
    #pragma unroll
    for (int i = 0; i < 8; i++) b4[i] = ld4(W, bbase + i * 4, f);

    f32x4 acc[4];
    #pragma unroll
    for (int nt = 0; nt < 4; nt++) acc[nt] = (f32x4){0.f, 0.f, 0.f, 0.f};

    for (int k0 = 0; k0 < 512; k0 += 64) {
        __syncthreads();
        *reinterpret_cast<uint4*>(&smA[arow * LDSTR + acol])     = packu4(a4[0], a4[1]);
        *reinterpret_cast<uint4*>(&smA[arow * LDSTR + acol + 8]) = packu4(a4[2], a4[3]);
        *reinterpret_cast<uint4*>(&smB[brow * LDSTR + bcol])      = packu4(b4[0], b4[1]);
        *reinterpret_cast<uint4*>(&smB[brow * LDSTR + bcol + 8])  = packu4(b4[2], b4[3]);
        *reinterpret_cast<uint4*>(&smB[brow * LDSTR + bcol + 16]) = packu4(b4[4], b4[5]);
        *reinterpret_cast<uint4*>(&smB[brow * LDSTR + bcol + 24]) = packu4(b4[6], b4[7]);
        __syncthreads();
        if (k0 + 64 < 512) {
            #pragma unroll
            for (int i = 0; i < 4; i++) a4[i] = ld4(A, abase + k0 + 64 + i * 4, f);
            #pragma unroll
            for (int i = 0; i < 8; i++) b4[i] = ld4(W, bbase + k0 + 64 + i * 4, f);
        }
        #pragma unroll
        for (int kk = 0; kk < 2; kk++) {
            bf16x8 af = *reinterpret_cast<const bf16x8*>(
                &smA[(w * 16 + l16) * LDSTR + kk * 32 + quad * 8]);
            #pragma unroll
            for (int nt = 0; nt < 4; nt++) {
                bf16x8 bfr = *reinterpret_cast<const bf16x8*>(
                    &smB[(nt * 16 + l16) * LDSTR + kk * 32 + quad * 8]);
                acc[nt] = __builtin_amdgcn_mfma_f32_16x16x32_bf16(af, bfr, acc[nt], 0, 0, 0);
            }
        }
    }

    const int b  = (row0 >= LSEQ) ? 1 : 0;
    const int lbase = row0 - b * LSEQ + w * 16;
    const int bh = b * NH + h;

    if (mode == 2) {
        float* Out = ws + OFF_VH;
        #pragma unroll
        for (int nt = 0; nt < 4; nt++) {
            int d = l16 + nt * 16;
            float bi = biasF[d];
            #pragma unroll
            for (int r = 0; r < 4; r++) {
                int l = lbase + quad * 4 + r;
                Out[(size_t)(bh * LSEQ + l) * 64 + d] = acc[nt][r] + bi;
            }
        }
    } else {
        #pragma unroll
        for (int nt = 0; nt < 4; nt++)
            #pragma unroll
            for (int r = 0; r < 4; r++)
                smA[(w * 16 + quad * 4 + r) * LDSTR + l16 + nt * 16] =
                    f2bf(acc[nt][r]);
        f32x4 acc2[4];
        #pragma unroll
        for (int nt = 0; nt < 4; nt++) acc2[nt] = (f32x4){0.f, 0.f, 0.f, 0.f};
        #pragma unroll
        for (int kk = 0; kk < 2; kk++) {
            bf16x8 af2 = *reinterpret_cast<const bf16x8*>(
                &smA[(w * 16 + l16) * LDSTR + kk * 32 + quad * 8]);
            #pragma unroll
            for (int nt = 0; nt < 4; nt++) {
                int od = nt * 16 + l16, j0 = kk * 32 + quad * 8;
                float4 wa = ld4(W1x, (size_t)od * 64 + j0, f);
                float4 wb = ld4(W1x, (size_t)od * 64 + j0 + 4, f);
                bf16x8 bfw = pack_bf8(wa, wb);
                acc2[nt] = __builtin_amdgcn_mfma_f32_16x16x32_bf16(af2, bfw, acc2[nt], 0, 0, 0);
            }
        }
        float* Out = ws + ((mode == 0) ? OFF_ETQ : OFF_ETK);
        #pragma unroll
        for (int nt = 0; nt < 4; nt++) {
            int d = l16 + nt * 16;
            float bi = biasF[d];
            #pragma unroll
            for (int r = 0; r < 4; r++) {
                int l = lbase + quad * 4 + r;
                Out[(size_t)(bh * LSEQ + l) * 64 + d] =
                    __expf(2.f * (acc2[nt][r] + bi));
            }
        }
    }
}

// ---------------------------------------------------------------------------
// Kernel 2: additive attention, TQ=8, 384 threads (t = k). Etq tile packed
// as bf16 pairs in [qi][d] layout: one ds_read_b128 serves 16 d-values of a
// q-row (DS instrs per 16-d chunk: 12 vs 48 in the [d][qi] f32 layout).
// Energy: e2 += vw_d * rcp(fma(Etq, Etk, 1.0)); no max-pass (|e| <~ 1).
// ---------------------------------------------------------------------------
__global__ __launch_bounds__(384, 6) void attn_kernel(
    const void* qp, const void* vwp, const void* vbp,
    const float* __restrict__ ws_in, float* __restrict__ ws,
    const int* __restrict__ mask, void* __restrict__ dout)
{
    __shared__ int s_cnt;
    const int f = block_detect((const unsigned int*)qp, &s_cnt);

    const float* Etq = ws_in + OFF_ETQ;
    const float* Etk = ws_in + OFF_ETK;
    const float* Vh  = ws_in + OFF_VH;
    float* Xh = ws + OFF_XH;

    const int bid = blockIdx.x;
    const int qt = bid % QTILES;
    const int bh = bid / QTILES;
    const int q0 = qt * TQ;
    const int b  = bh >> 3;
    const int h  = bh & 7;
    const int t  = threadIdx.x;
    const int wave = t >> 6;

    __shared__ __align__(16) unsigned etqb[TQ][36];   // bf16-pair packed, 32 used
    __shared__ __align__(16) float vws[64];
    __shared__ float ps[TQ][LSEQ];
    __shared__ float red[6][TQ][16][4];
    __shared__ float rsum[TQ][6];
    __shared__ float s_vb;

    // stage Etq tile bf16-packed [qi][d-pair] and vw
    for (int i = t; i < TQ * 32; i += 384) {
        int qi = i >> 5, c = i & 31;
        const float* row = Etq + (size_t)(bh * LSEQ + q0 + qi) * 64;
        etqb[qi][c] = pk_bf16(row[2 * c], row[2 * c + 1]);
    }
    if (t < 64) {
        float v = ld1(vwp, t, f);
        vws[t] = v;
        #pragma unroll
        for (int off = 32; off > 0; off >>= 1) v += __shfl_xor(v, off, 64);
        if (t == 0) s_vb = ld1(vbp, 0, f) + v;
    }
    const int mok = mask[b * LSEQ + t];
    __syncthreads();
    const float vbSum = s_vb;

    float e2[TQ] = {0.f, 0.f, 0.f, 0.f, 0.f, 0.f, 0.f, 0.f};
    const float* ekrow = Etk + (size_t)(bh * LSEQ + t) * 64;
    #pragma unroll
    for (int dc = 0; dc < 4; dc++) {                // 16 d per chunk
        float4 ek[4], wv[4];
        #pragma unroll
        for (int i = 0; i < 4; i++) {
            ek[i] = *reinterpret_cast<const float4*>(ekrow + dc * 16 + i * 4);
            wv[i] = *reinterpret_cast<const float4*>(&vws[dc * 16 + i * 4]);
        }
        #pragma unroll
        for (int qi = 0; qi < TQ; qi++) {
            uint4 eu = *reinterpret_cast<const uint4*>(&etqb[qi][dc * 8]);
            const unsigned us[4] = {eu.x, eu.y, eu.z, eu.w};
            float acc = e2[qi];
            #pragma unroll
            for (int j2 = 0; j2 < 4; j2++) {        // each uint4 elem = 2 uints? no: 4 uints = 8 d
                unsigned u = us[j2];
                float elo = __uint_as_float(u << 16);
                float ehi = __uint_as_float(u & 0xFFFF0000u);
                // uint j2 covers d = dc*16 + j2*2, +1  (first uint4 half)
                // mapping to ek/wv: float4 idx = (j2*2)/4 = j2>>1, comps (j2*2)&3
                float eklo = (j2 & 1) ? ((j2 >> 1) ? 0.f : 0.f) : 0.f;  // replaced below
                (void)eklo;
                acc = acc; // placeholder removed in expansion below
                float ekl = ((j2 == 0) ? ek[0].x : (j2 == 1) ? ek[0].z
                           : (j2 == 2) ? ek[1].x : ek[1].z);
                float ekh = ((j2 == 0) ? ek[0].y : (j2 == 1) ? ek[0].w
                           : (j2 == 2) ? ek[1].y : ek[1].w);
                float wl  = ((j2 == 0) ? wv[0].x : (j2 == 1) ? wv[0].z
                           : (j2 == 2) ? wv[1].x : wv[1].z);
                float wh  = ((j2 == 0) ? wv[0].y : (j2 == 1) ? wv[0].w
                           : (j2 == 2) ? wv[1].y : wv[1].w);
                acc = fmaf(wl, __builtin_amdgcn_rcpf(fmaf(elo, ekl, 1.0f)), acc);
                acc = fmaf(wh, __builtin_amdgcn_rcpf(fmaf(ehi, ekh, 1.0f)), acc);
            }
            // second uint4: d = dc*16 + 8 + j2*2
            uint4 eu2 = *reinterpret_cast<const uint4*>(&etqb[qi][dc * 8 + 4]);
            const unsigned us2[4] = {eu2.x, eu2.y, eu2.z, eu2.w};
            #pragma unroll
            for (int j2 = 0; j2 < 4; j2++) {
                unsigned u = us2[j2];
                float elo = __uint_as_float(u << 16);
                float ehi = __uint_as_float(u & 0xFFFF0000u);
                float ekl = ((j2 == 0) ? ek[2].x : (j2 == 1) ? ek[2].z
                           : (j2 == 2) ? ek[3].x : ek[3].z);
                float ekh = ((j2 == 0) ? ek[2].y : (j2 == 1) ? ek[2].w
                           : (j2 == 2) ? ek[3].y : ek[3].w);
                float wl  = ((j2 == 0) ? wv[2].x : (j2 == 1) ? wv[2].z
                           : (j2 == 2) ? wv[3].x : wv[3].z);
                float wh  = ((j2 == 0) ? wv[2].y : (j2 == 1) ? wv[2].w
                           : (j2 == 2) ? wv[3].y : wv[3].w);
                acc = fmaf(wl, __builtin_amdgcn_rcpf(fmaf(elo, ekl, 1.0f)), acc);
                acc = fmaf(wh, __builtin_amdgcn_rcpf(fmaf(ehi, ekh, 1.0f)), acc);
            }
            e2[qi] = acc;
        }
    }

    float p[TQ];
    #pragma unroll
    for (int qi = 0; qi < TQ; qi++) {
        float en = fmaf(-2.0f, e2[qi], vbSum);
        if (mok == 0) en = -1e10f;
        p[qi] = __expf(en);
        float s = p[qi];
        #pragma unroll
        for (int off = 32; off > 0; off >>= 1) s += __shfl_xor(s, off, 64);
        if ((t & 63) == 0) rsum[qi][wave] = s;
    }
    __syncthreads();
    #pragma unroll
    for (int qi = 0; qi < TQ; qi++) {
        float gs = rsum[qi][0] + rsum[qi][1] + rsum[qi][2] +
                   rsum[qi][3] + rsum[qi][4] + rsum[qi][5];
        p[qi] *= 1.0f / gs;
        ps[qi][t] = p[qi];
        size_t aidx = XELEMS + (size_t)(bh * LSEQ + q0 + qi) * LSEQ + t;
        if (f) ((float*)dout)[aidx] = p[qi];
        else   ((ushort_t*)dout)[aidx] = f2bf(p[qi]);
    }
    __syncthreads();

    const int dq = t & 15;
    const int ksub = t >> 4;
    const float* vb4 = Vh + (size_t)bh * LSEQ * 64 + dq * 4;
    float4 acc[TQ];
    #pragma unroll
    for (int qi = 0; qi < TQ; qi++) acc[qi] = make_float4(0.f, 0.f, 0.f, 0.f);
    for (int kk = ksub; kk < LSEQ; kk += 24) {
        float4 v4 = *reinterpret_cast<const float4*>(vb4 + (size_t)kk * 64);
        #pragma unroll
        for (int qi = 0; qi < TQ; qi++) {
            float pq = ps[qi][kk];
            acc[qi].x = fmaf(pq, v4.x, acc[qi].x);
            acc[qi].y = fmaf(pq, v4.y, acc[qi].y);
            acc[qi].z = fmaf(pq, v4.z, acc[qi].z);
            acc[qi].w = fmaf(pq, v4.w, acc[qi].w);
        }
    }
    #pragma unroll
    for (int qi = 0; qi < TQ; qi++) {
        #pragma unroll
        for (int off = 16; off <= 32; off <<= 1) {
            acc[qi].x += __shfl_xor(acc[qi].x, off, 64);
            acc[qi].y += __shfl_xor(acc[qi].y, off, 64);
            acc[qi].z += __shfl_xor(acc[qi].z, off, 64);
            acc[qi].w += __shfl_xor(acc[qi].w, off, 64);
        }
    }
    if ((t & 63) < 16) {
        #pragma unroll
        for (int qi = 0; qi < TQ; qi++) {
            red[wave][qi][dq][0] = acc[qi].x;
            red[wave][qi][dq][1] = acc[qi].y;
            red[wave][qi][dq][2] = acc[qi].z;
            red[wave][qi][dq][3] = acc[qi].w;
        }
    }
    __syncthreads();
    if (t < 256) {
        int d = t & 63;
        #pragma unroll
        for (int half = 0; half < 2; half++) {
            int qi = (t >> 6) + half * 4;
            float sx = 0.f;
            #pragma unroll
            for (int w = 0; w < 6; w++) sx += red[w][qi][d >> 2][d & 3];
            Xh[((size_t)(b * LSEQ + q0 + qi) * NH + h) * 64 + d] = sx;
        }
    }
}

// ---------------------------------------------------------------------------
// Kernel 3: output projection via bf16 MFMA (r12, unchanged).
// ---------------------------------------------------------------------------
__global__ __launch_bounds__(128) void gemm_out(
    const void* qp, const void* Wop, const void* bop,
    const float* __restrict__ ws_in, void* __restrict__ dout)
{
    __shared__ int s_cnt;
    __shared__ ushort_t smA[32 * LDSTR];
    __shared__ ushort_t smB[64 * LDSTR];
    __shared__ float biasF[64];
    const int f = block_detect((const unsigned int*)qp, &s_cnt);

    const float* Xh = ws_in + OFF_XH;
    const int col0 = blockIdx.x * 64;
    const int row0 = blockIdx.y * 32;
    const int t = threadIdx.x;
    const int w = t >> 6, l16 = t & 15, quad = (t & 63) >> 4;

    if (t < 64) biasF[t] = ld1(bop, col0 + t, f);

    const int arow = t >> 2, acol = (t & 3) * 16;
    const int brow = t >> 1, bcol = (t & 1) * 32;
    const float* Ab = Xh + (size_t)(row0 + arow) * 512 + acol;
    const size_t bbase = (size_t)(col0 + brow) * 512 + bcol;

    float4 a4[4], b4[8];
    #pragma unroll
    for (int i = 0; i < 4; i++) a4[i] = *reinterpret_cast<const float4*>(Ab + i * 4);
    #pragma unroll
    for (int i = 0; i < 8; i++) b4[i] = ld4(Wop, bbase + i * 4, f);

    f32x4 acc[4];
    #pragma unroll
    for (int nt = 0; nt < 4; nt++) acc[nt] = (f32x4){0.f, 0.f, 0.f, 0.f};

    for (int k0 = 0; k0 < 512; k0 += 64) {
        __syncthreads();
        *reinterpret_cast<uint4*>(&smA[arow * LDSTR + acol])     = packu4(a4[0], a4[1]);
        *reinterpret_cast<uint4*>(&smA[arow * LDSTR + acol + 8]) = packu4(a4[2], a4[3]);
        *reinterpret_cast<uint4*>(&smB[brow * LDSTR + bcol])      = packu4(b4[0], b4[1]);
        *reinterpret_cast<uint4*>(&smB[brow * LDSTR + bcol + 8])  = packu4(b4[2], b4[3]);
        *reinterpret_cast<uint4*>(&smB[brow * LDSTR + bcol + 16]) = packu4(b4[4], b4[5]);
        *reinterpret_cast<uint4*>(&smB[brow * LDSTR + bcol + 24]) = packu4(b4[6], b4[7]);
        __syncthreads();
        if (k0 + 64 < 512) {
            #pragma unroll
            for (int i = 0; i < 4; i++)
                a4[i] = *reinterpret_cast<const float4*>(Ab + k0 + 64 + i * 4);
            #pragma unroll
            for (int i = 0; i < 8; i++) b4[i] = ld4(Wop, bbase + k0 + 64 + i * 4, f);
        }
        #pragma unroll
        for (int kk = 0; kk < 2; kk++) {
            bf16x8 af = *reinterpret_cast<const bf16x8*>(
                &smA[(w * 16 + l16) * LDSTR + kk * 32 + quad * 8]);
            #pragma unroll
            for (int nt = 0; nt < 4; nt++) {
                bf16x8 bfr = *reinterpret_cast<const bf16x8*>(
                    &smB[(nt * 16 + l16) * LDSTR + kk * 32 + quad * 8]);
                acc[nt] = __builtin_amdgcn_mfma_f32_16x16x32_bf16(af, bfr, acc[nt], 0, 0, 0);
            }
        }
    }

    #pragma unroll
    for (int nt = 0; nt < 4; nt++) {
        int n = col0 + l16 + nt * 16;
        float bi = biasF[l16 + nt * 16];
        #pragma unroll
        for (int r = 0; r < 4; r++) {
            int m = row0 + w * 16 + quad * 4 + r;
            float c = acc[nt][r] + bi;
            size_t idx = (size_t)m * 512 + n;
            if (f) ((float*)dout)[idx] = c;
            else   ((ushort_t*)dout)[idx] = f2bf(c);
        }
    }
}

// ---------------------------------------------------------------------------
extern "C" void kernel_launch(void* const* d_in, const int* in_sizes, int n_in,
                              void* d_out, int out_size, void* d_ws, size_t ws_size,
                              hipStream_t stream)
{
    const void* qp = d_in[0];
    const void* kp = d_in[1];
    const void* vp = d_in[2];
    const int* mask = (const int*)d_in[3];
    const void* Wqp = d_in[4];  const void* bqp = d_in[5];
    const void* Wkp = d_in[6];  const void* bkp = d_in[7];
    const void* Wvp = d_in[8];  const void* bvp = d_in[9];
    const void* Wop = d_in[10]; const void* bop = d_in[11];
    const void* W1p = d_in[12]; const void* b1p = d_in[13];
    const void* W2p = d_in[14]; const void* b2p = d_in[15];
    const void* vwp = d_in[16]; const void* vbp = d_in[17];

    float* ws = (float*)d_ws;

    gemm_qkv<<<dim3(8, 24, 3), 128, 0, stream>>>(qp, kp, vp, Wqp, Wkp, Wvp,
                                                 W1p, W2p, bqp, bkp, b1p, b2p,
                                                 bvp, ws);
    attn_kernel<<<BH * QTILES, 384, 0, stream>>>(qp, vwp, vbp, ws, ws, mask, d_out);
    gemm_out<<<dim3(8, 24, 1), 128, 0, stream>>>(qp, Wop, bop, ws, d_out);
}

// Round 14
// 165.039 us; speedup vs baseline: 1.6534x; 1.6534x over previous
//
#include <hip/hip_runtime.h>

// Problem constants
#define BATCH 2
#define LSEQ 384
#define NHID 512
#define NH 8
#define DH 64
#define BH (BATCH*NH)          // 16
#define XELEMS ((size_t)768 * NHID)        // 393216 (x output elems)
#define TQ 8                   // q-rows per attn block
#define QTILES (LSEQ/TQ)       // 48

typedef unsigned short ushort_t;
typedef __attribute__((ext_vector_type(8))) short bf16x8;
typedef __attribute__((ext_vector_type(4))) float f32x4;

__device__ __forceinline__ float bf2f(ushort_t u) {
    unsigned int v = ((unsigned int)u) << 16;
    return __uint_as_float(v);
}
__device__ __forceinline__ ushort_t f2bf(float f) {
    unsigned int u = __float_as_uint(f);
    unsigned int lsb = (u >> 16) & 1u;
    u += 0x7fffu + lsb;           // round-to-nearest-even
    return (ushort_t)(u >> 16);
}
// RNE bf16 pair-pack: 2x add + v_perm (ushort0=bf16(a), ushort1=bf16(b))
__device__ __forceinline__ unsigned pk_bf16(float a, float b) {
    unsigned ua = __float_as_uint(a), ub = __float_as_uint(b);
    ua += 0x7fffu + ((ua >> 16) & 1u);
    ub += 0x7fffu + ((ub >> 16) & 1u);
    return __builtin_amdgcn_perm(ub, ua, 0x07060302);
}
__device__ __forceinline__ float ld1(const void* p, size_t i, int f) {
    return f ? ((const float*)p)[i] : bf2f(((const ushort_t*)p)[i]);
}
__device__ __forceinline__ float4 ld4(const void* p, size_t i, int f) {
    if (f) return ((const float4*)p)[i >> 2];
    ushort4 u = ((const ushort4*)p)[i >> 2];
    return make_float4(bf2f(u.x), bf2f(u.y), bf2f(u.z), bf2f(u.w));
}
__device__ __forceinline__ int block_detect(const unsigned int* q, int* cnt) {
    int t = threadIdx.x;
    if (t == 0) *cnt = 0;
    __syncthreads();
    int n = blockDim.x < 256 ? blockDim.x : 256;
    if (t < n) {
        unsigned int elo = (q[t] >> 7) & 0xFFu;
        if (elo >= 100u && elo <= 150u) atomicAdd(cnt, 1);
    }
    __syncthreads();
    return (*cnt * 2 > n) ? 0 : 1;     // 0 = bf16-packed, 1 = fp32
}
__device__ __forceinline__ uint4 packu4(float4 a, float4 b) {
    uint4 r;
    r.x = pk_bf16(a.x, a.y); r.y = pk_bf16(a.z, a.w);
    r.z = pk_bf16(b.x, b.y); r.w = pk_bf16(b.z, b.w);
    return r;
}
__device__ __forceinline__ bf16x8 pack_bf8(float4 a, float4 b) {
    union { uint4 u; bf16x8 v; } r;
    r.u = packu4(a, b);
    return r.v;
}

// ---------------- workspace layout (float offsets) ----------------
#define OFF_ETQ   16                  // Etq = exp(2 tq)  [bh][l][d]
#define OFF_ETK   (16 + 393216)       // Etk = exp(2 tk)  [bh][l][d] (row-major)
#define OFF_VH    (16 + 2*393216)     // V                [bh][l][d]
#define OFF_XH    (16 + 3*393216)     // context [B,L,H,D]

#define LDSTR 72   // LDS row stride in ushorts (144 B)

// ---------------------------------------------------------------------------
// Kernel 1: QKV projection via bf16 MFMA. 32(m) x 64(n=head) tile, 128 thr
// (2 waves), K=512 step 64, reg prefetch. Modes 0/1 fold W1/W2 via a second
// in-register MFMA pass and write Etq/Etk = exp(2(..+biasF)) row-major;
// mode 2 writes V + bv.
// ---------------------------------------------------------------------------
__global__ __launch_bounds__(128) void gemm_qkv(
    const void* qp, const void* kp, const void* vp,
    const void* Wqp, const void* Wkp, const void* Wvp,
    const void* W1p, const void* W2p,
    const void* bqp, const void* bkp, const void* b1p, const void* b2p,
    const void* bvp, float* __restrict__ ws)
{
    __shared__ int s_cnt;
    __shared__ ushort_t smA[32 * LDSTR];
    __shared__ ushort_t smB[64 * LDSTR];
    __shared__ float biasF[64];
    const int f = block_detect((const unsigned int*)qp, &s_cnt);

    const int mode = blockIdx.z;
    const void* A = (mode == 0) ? qp : (mode == 1) ? kp : vp;
    const void* W = (mode == 0) ? Wqp : (mode == 1) ? Wkp : Wvp;
    const void* W1x = (mode == 1) ? W2p : W1p;

    const int h    = blockIdx.x;
    const int col0 = h * 64;
    const int row0 = blockIdx.y * 32;
    const int t = threadIdx.x;
    const int w = t >> 6, l16 = t & 15, quad = (t & 63) >> 4;

    // fused bias into LDS (threads 0..63), overlapped with prefetch
    if (t < 64) {
        if (mode == 2) {
            biasF[t] = ld1(bvp, col0 + t, f);
        } else {
            const void* b1x = (mode == 1) ? b2p : b1p;
            const void* bx  = (mode == 1) ? bkp : bqp;
            float s = ld1(b1x, t, f);
            for (int j = 0; j < 64; j++)
                s = fmaf(ld1(W1x, (size_t)t * 64 + j, f), ld1(bx, h * 64 + j, f), s);
            biasF[t] = s;
        }
    }

    const int arow = t >> 2, acol = (t & 3) * 16;
    const int brow = t >> 1, bcol = (t & 1) * 32;
    const size_t abase = (size_t)(row0 + arow) * 512 + acol;
    const size_t bbase = (size_t)(col0 + brow) * 512 + bcol;

    float4 a4[4], b4[8];
    #pragma unroll
    for (int i = 0; i < 4; i++) a4[i] = ld4(A, abase + i * 4, f);
    #pragma unroll
    for (int i = 0; i < 8; i++) b4[i] = ld4(W, bbase + i * 4, f);

    f32x4 acc[4];
    #pragma unroll
    for (int nt = 0; nt < 4; nt++) acc[nt] = (f32x4){0.f, 0.f, 0.f, 0.f};

    for (int k0 = 0; k0 < 512; k0 += 64) {
        __syncthreads();
        *reinterpret_cast<uint4*>(&smA[arow * LDSTR + acol])     = packu4(a4[0], a4[1]);
        *reinterpret_cast<uint4*>(&smA[arow * LDSTR + acol + 8]) = packu4(a4[2], a4[3]);
        *reinterpret_cast<uint4*>(&smB[brow * LDSTR + bcol])      = packu4(b4[0], b4[1]);
        *reinterpret_cast<uint4*>(&smB[brow * LDSTR + bcol + 8])  = packu4(b4[2], b4[3]);
        *reinterpret_cast<uint4*>(&smB[brow * LDSTR + bcol + 16]) = packu4(b4[4], b4[5]);
        *reinterpret_cast<uint4*>(&smB[brow * LDSTR + bcol + 24]) = packu4(b4[6], b4[7]);
        __syncthreads();
        if (k0 + 64 < 512) {
            #pragma unroll
            for (int i = 0; i < 4; i++) a4[i] = ld4(A, abase + k0 + 64 + i * 4, f);
            #pragma unroll
            for (int i = 0; i < 8; i++) b4[i] = ld4(W, bbase + k0 + 64 + i * 4, f);
        }
        #pragma unroll
        for (int kk = 0; kk < 2; kk++) {
            bf16x8 af = *reinterpret_cast<const bf16x8*>(
                &smA[(w * 16 + l16) * LDSTR + kk * 32 + quad * 8]);
            #pragma unroll
            for (int nt = 0; nt < 4; nt++) {
                bf16x8 bfr = *reinterpret_cast<const bf16x8*>(
                    &smB[(nt * 16 + l16) * LDSTR + kk * 32 + quad * 8]);
                acc[nt] = __builtin_amdgcn_mfma_f32_16x16x32_bf16(af, bfr, acc[nt], 0, 0, 0);
            }
        }
    }

    const int b  = (row0 >= LSEQ) ? 1 : 0;
    const int lbase = row0 - b * LSEQ + w * 16;
    const int bh = b * NH + h;

    if (mode == 2) {
        float* Out = ws + OFF_VH;
        #pragma unroll
        for (int nt = 0; nt < 4; nt++) {
            int d = l16 + nt * 16;
            float bi = biasF[d];
            #pragma unroll
            for (int r = 0; r < 4; r++) {
                int l = lbase + quad * 4 + r;
                Out[(size_t)(bh * LSEQ + l) * 64 + d] = acc[nt][r] + bi;
            }
        }
    } else {
        // ---- fold: restage acc (bf16) in wave-private LDS rows, x W1^T ----
        #pragma unroll
        for (int nt = 0; nt < 4; nt++)
            #pragma unroll
            for (int r = 0; r < 4; r++)
                smA[(w * 16 + quad * 4 + r) * LDSTR + l16 + nt * 16] =
                    f2bf(acc[nt][r]);
        f32x4 acc2[4];
        #pragma unroll
        for (int nt = 0; nt < 4; nt++) acc2[nt] = (f32x4){0.f, 0.f, 0.f, 0.f};
        #pragma unroll
        for (int kk = 0; kk < 2; kk++) {
            bf16x8 af2 = *reinterpret_cast<const bf16x8*>(
                &smA[(w * 16 + l16) * LDSTR + kk * 32 + quad * 8]);
            #pragma unroll
            for (int nt = 0; nt < 4; nt++) {
                int od = nt * 16 + l16, j0 = kk * 32 + quad * 8;
                float4 wa = ld4(W1x, (size_t)od * 64 + j0, f);
                float4 wb = ld4(W1x, (size_t)od * 64 + j0 + 4, f);
                bf16x8 bfw = pack_bf8(wa, wb);
                acc2[nt] = __builtin_amdgcn_mfma_f32_16x16x32_bf16(af2, bfw, acc2[nt], 0, 0, 0);
            }
        }
        float* Out = ws + ((mode == 0) ? OFF_ETQ : OFF_ETK);   // both row-major
        #pragma unroll
        for (int nt = 0; nt < 4; nt++) {
            int d = l16 + nt * 16;
            float bi = biasF[d];
            #pragma unroll
            for (int r = 0; r < 4; r++) {
                int l = lbase + quad * 4 + r;
                Out[(size_t)(bh * LSEQ + l) * 64 + d] =
                    __expf(2.f * (acc2[nt][r] + bi));
            }
        }
    }
}

// ---------------------------------------------------------------------------
// Kernel 2: additive attention, TQ=8, 384 threads (t = k). Etk row-major:
// thread t reads its Etk row via 16 b128 loads (deep MLP, L1 reuse).
// Energy: e2 += vw_d * rcp(fma(Etq, Etk, 1.0)); no max-pass (|e| <~ 1).
// NOTE (r13 post-mortem): do NOT add per-thread arrays to the energy loop —
// under __launch_bounds__(384,6) they spill to scratch (372 MB FETCH, 3x dur).
// ---------------------------------------------------------------------------
__global__ __launch_bounds__(384, 6) void attn_kernel(
    const void* qp, const void* vwp, const void* vbp,
    const float* __restrict__ ws_in, float* __restrict__ ws,
    const int* __restrict__ mask, void* __restrict__ dout)
{
    __shared__ int s_cnt;
    const int f = block_detect((const unsigned int*)qp, &s_cnt);

    const float* Etq = ws_in + OFF_ETQ;
    const float* Etk = ws_in + OFF_ETK;
    const float* Vh  = ws_in + OFF_VH;
    float* Xh = ws + OFF_XH;

    const int bid = blockIdx.x;
    const int qt = bid % QTILES;
    const int bh = bid / QTILES;
    const int q0 = qt * TQ;
    const int b  = bh >> 3;
    const int h  = bh & 7;
    const int t  = threadIdx.x;
    const int wave = t >> 6;

    __shared__ __align__(16) float etq8[64][TQ];
    __shared__ float vws[64];
    __shared__ float ps[TQ][LSEQ];
    __shared__ float red[6][TQ][16][4];
    __shared__ float rsum[TQ][6];
    __shared__ float s_vb;

    for (int i = t; i < TQ * 64; i += 384) {
        int qi = i >> 6, d = i & 63;
        etq8[d][qi] = Etq[(size_t)(bh * LSEQ + q0 + qi) * 64 + d];
    }
    if (t < 64) {
        float v = ld1(vwp, t, f);
        vws[t] = v;
        #pragma unroll
        for (int off = 32; off > 0; off >>= 1) v += __shfl_xor(v, off, 64);
        if (t == 0) s_vb = ld1(vbp, 0, f) + v;
    }
    const int mok = mask[b * LSEQ + t];
    __syncthreads();
    const float vbSum = s_vb;

    float e2[TQ] = {0.f, 0.f, 0.f, 0.f, 0.f, 0.f, 0.f, 0.f};
    const float* ekrow = Etk + (size_t)(bh * LSEQ + t) * 64;
    #pragma unroll 4
    for (int dv = 0; dv < 16; dv++) {
        float4 ek4 = *reinterpret_cast<const float4*>(ekrow + dv * 4);
        #pragma unroll
        for (int j = 0; j < 4; j++) {
            int d = dv * 4 + j;
            float ekv = (j == 0) ? ek4.x : (j == 1) ? ek4.y : (j == 2) ? ek4.z : ek4.w;
            float4 eqA = *reinterpret_cast<const float4*>(&etq8[d][0]);
            float4 eqB = *reinterpret_cast<const float4*>(&etq8[d][4]);
            float wv = vws[d];
            e2[0] = fmaf(wv, __builtin_amdgcn_rcpf(fmaf(eqA.x, ekv, 1.0f)), e2[0]);
            e2[1] = fmaf(wv, __builtin_amdgcn_rcpf(fmaf(eqA.y, ekv, 1.0f)), e2[1]);
            e2[2] = fmaf(wv, __builtin_amdgcn_rcpf(fmaf(eqA.z, ekv, 1.0f)), e2[2]);
            e2[3] = fmaf(wv, __builtin_amdgcn_rcpf(fmaf(eqA.w, ekv, 1.0f)), e2[3]);
            e2[4] = fmaf(wv, __builtin_amdgcn_rcpf(fmaf(eqB.x, ekv, 1.0f)), e2[4]);
            e2[5] = fmaf(wv, __builtin_amdgcn_rcpf(fmaf(eqB.y, ekv, 1.0f)), e2[5]);
            e2[6] = fmaf(wv, __builtin_amdgcn_rcpf(fmaf(eqB.z, ekv, 1.0f)), e2[6]);
            e2[7] = fmaf(wv, __builtin_amdgcn_rcpf(fmaf(eqB.w, ekv, 1.0f)), e2[7]);
        }
    }

    float p[TQ];
    #pragma unroll
    for (int qi = 0; qi < TQ; qi++) {
        float en = fmaf(-2.0f, e2[qi], vbSum);
        if (mok == 0) en = -1e10f;
        p[qi] = __expf(en);
        float s = p[qi];
        #pragma unroll
        for (int off = 32; off > 0; off >>= 1) s += __shfl_xor(s, off, 64);
        if ((t & 63) == 0) rsum[qi][wave] = s;
    }
    __syncthreads();
    #pragma unroll
    for (int qi = 0; qi < TQ; qi++) {
        float gs = rsum[qi][0] + rsum[qi][1] + rsum[qi][2] +
                   rsum[qi][3] + rsum[qi][4] + rsum[qi][5];
        p[qi] *= 1.0f / gs;
        ps[qi][t] = p[qi];
        size_t aidx = XELEMS + (size_t)(bh * LSEQ + q0 + qi) * LSEQ + t;
        if (f) ((float*)dout)[aidx] = p[qi];
        else   ((ushort_t*)dout)[aidx] = f2bf(p[qi]);
    }
    __syncthreads();

    const int dq = t & 15;
    const int ksub = t >> 4;
    const float* vb4 = Vh + (size_t)bh * LSEQ * 64 + dq * 4;
    float4 acc[TQ];
    #pragma unroll
    for (int qi = 0; qi < TQ; qi++) acc[qi] = make_float4(0.f, 0.f, 0.f, 0.f);
    for (int kk = ksub; kk < LSEQ; kk += 24) {
        float4 v4 = *reinterpret_cast<const float4*>(vb4 + (size_t)kk * 64);
        #pragma unroll
        for (int qi = 0; qi < TQ; qi++) {
            float pq = ps[qi][kk];
            acc[qi].x = fmaf(pq, v4.x, acc[qi].x);
            acc[qi].y = fmaf(pq, v4.y, acc[qi].y);
            acc[qi].z = fmaf(pq, v4.z, acc[qi].z);
            acc[qi].w = fmaf(pq, v4.w, acc[qi].w);
        }
    }
    #pragma unroll
    for (int qi = 0; qi < TQ; qi++) {
        #pragma unroll
        for (int off = 16; off <= 32; off <<= 1) {
            acc[qi].x += __shfl_xor(acc[qi].x, off, 64);
            acc[qi].y += __shfl_xor(acc[qi].y, off, 64);
            acc[qi].z += __shfl_xor(acc[qi].z, off, 64);
            acc[qi].w += __shfl_xor(acc[qi].w, off, 64);
        }
    }
    if ((t & 63) < 16) {
        #pragma unroll
        for (int qi = 0; qi < TQ; qi++) {
            red[wave][qi][dq][0] = acc[qi].x;
            red[wave][qi][dq][1] = acc[qi].y;
            red[wave][qi][dq][2] = acc[qi].z;
            red[wave][qi][dq][3] = acc[qi].w;
        }
    }
    __syncthreads();
    if (t < 256) {
        int d = t & 63;
        #pragma unroll
        for (int half = 0; half < 2; half++) {
            int qi = (t >> 6) + half * 4;
            float sx = 0.f;
            #pragma unroll
            for (int w = 0; w < 6; w++) sx += red[w][qi][d >> 2][d & 3];
            Xh[((size_t)(b * LSEQ + q0 + qi) * NH + h) * 64 + d] = sx;
        }
    }
}

// ---------------------------------------------------------------------------
// Kernel 3: output projection via bf16 MFMA. x = Xh @ Wo^T + bo, dual-dtype.
// ---------------------------------------------------------------------------
__global__ __launch_bounds__(128) void gemm_out(
    const void* qp, const void* Wop, const void* bop,
    const float* __restrict__ ws_in, void* __restrict__ dout)
{
    __shared__ int s_cnt;
    __shared__ ushort_t smA[32 * LDSTR];
    __shared__ ushort_t smB[64 * LDSTR];
    __shared__ float biasF[64];
    const int f = block_detect((const unsigned int*)qp, &s_cnt);

    const float* Xh = ws_in + OFF_XH;
    const int col0 = blockIdx.x * 64;
    const int row0 = blockIdx.y * 32;
    const int t = threadIdx.x;
    const int w = t >> 6, l16 = t & 15, quad = (t & 63) >> 4;

    if (t < 64) biasF[t] = ld1(bop, col0 + t, f);

    const int arow = t >> 2, acol = (t & 3) * 16;
    const int brow = t >> 1, bcol = (t & 1) * 32;
    const float* Ab = Xh + (size_t)(row0 + arow) * 512 + acol;
    const size_t bbase = (size_t)(col0 + brow) * 512 + bcol;

    float4 a4[4], b4[8];
    #pragma unroll
    for (int i = 0; i < 4; i++) a4[i] = *reinterpret_cast<const float4*>(Ab + i * 4);
    #pragma unroll
    for (int i = 0; i < 8; i++) b4[i] = ld4(Wop, bbase + i * 4, f);

    f32x4 acc[4];
    #pragma unroll
    for (int nt = 0; nt < 4; nt++) acc[nt] = (f32x4){0.f, 0.f, 0.f, 0.f};

    for (int k0 = 0; k0 < 512; k0 += 64) {
        __syncthreads();
        *reinterpret_cast<uint4*>(&smA[arow * LDSTR + acol])     = packu4(a4[0], a4[1]);
        *reinterpret_cast<uint4*>(&smA[arow * LDSTR + acol + 8]) = packu4(a4[2], a4[3]);
        *reinterpret_cast<uint4*>(&smB[brow * LDSTR + bcol])      = packu4(b4[0], b4[1]);
        *reinterpret_cast<uint4*>(&smB[brow * LDSTR + bcol + 8])  = packu4(b4[2], b4[3]);
        *reinterpret_cast<uint4*>(&smB[brow * LDSTR + bcol + 16]) = packu4(b4[4], b4[5]);
        *reinterpret_cast<uint4*>(&smB[brow * LDSTR + bcol + 24]) = packu4(b4[6], b4[7]);
        __syncthreads();
        if (k0 + 64 < 512) {
            #pragma unroll
            for (int i = 0; i < 4; i++)
                a4[i] = *reinterpret_cast<const float4*>(Ab + k0 + 64 + i * 4);
            #pragma unroll
            for (int i = 0; i < 8; i++) b4[i] = ld4(Wop, bbase + k0 + 64 + i * 4, f);
        }
        #pragma unroll
        for (int kk = 0; kk < 2; kk++) {
            bf16x8 af = *reinterpret_cast<const bf16x8*>(
                &smA[(w * 16 + l16) * LDSTR + kk * 32 + quad * 8]);
            #pragma unroll
            for (int nt = 0; nt < 4; nt++) {
                bf16x8 bfr = *reinterpret_cast<const bf16x8*>(
                    &smB[(nt * 16 + l16) * LDSTR + kk * 32 + quad * 8]);
                acc[nt] = __builtin_amdgcn_mfma_f32_16x16x32_bf16(af, bfr, acc[nt], 0, 0, 0);
            }
        }
    }

    #pragma unroll
    for (int nt = 0; nt < 4; nt++) {
        int n = col0 + l16 + nt * 16;
        float bi = biasF[l16 + nt * 16];
        #pragma unroll
        for (int r = 0; r < 4; r++) {
            int m = row0 + w * 16 + quad * 4 + r;
            float c = acc[nt][r] + bi;
            size_t idx = (size_t)m * 512 + n;
            if (f) ((float*)dout)[idx] = c;
            else   ((ushort_t*)dout)[idx] = f2bf(c);
        }
    }
}

// ---------------------------------------------------------------------------
extern "C" void kernel_launch(void* const* d_in, const int* in_sizes, int n_in,
                              void* d_out, int out_size, void* d_ws, size_t ws_size,
                              hipStream_t stream)
{
    const void* qp = d_in[0];
    const void* kp = d_in[1];
    const void* vp = d_in[2];
    const int* mask = (const int*)d_in[3];
    const void* Wqp = d_in[4];  const void* bqp = d_in[5];
    const void* Wkp = d_in[6];  const void* bkp = d_in[7];
    const void* Wvp = d_in[8];  const void* bvp = d_in[9];
    const void* Wop = d_in[10]; const void* bop = d_in[11];
    const void* W1p = d_in[12]; const void* b1p = d_in[13];
    const void* W2p = d_in[14]; const void* b2p = d_in[15];
    const void* vwp = d_in[16]; const void* vbp = d_in[17];

    float* ws = (float*)d_ws;

    gemm_qkv<<<dim3(8, 24, 3), 128, 0, stream>>>(qp, kp, vp, Wqp, Wkp, Wvp,
                                                 W1p, W2p, bqp, bkp, b1p, b2p,
                                                 bvp, ws);
    attn_kernel<<<BH * QTILES, 384, 0, stream>>>(qp, vwp, vbp, ws, ws, mask, d_out);
    gemm_out<<<dim3(8, 24, 1), 128, 0, stream>>>(qp, Wop, bop, ws, d_out);
}